// Round 3
// baseline (180.352 us; speedup 1.0000x reference)
//
#include <hip/hip_runtime.h>
#include <cstdint>

typedef __attribute__((ext_vector_type(8))) short short8;
typedef __attribute__((ext_vector_type(4))) float f32x4;

#define LOG2E 1.44269504088896340736f

static __device__ __forceinline__ float bf2f(unsigned short u) {
    union { unsigned int i; float f; } v; v.i = ((unsigned int)u) << 16; return v.f;
}
static __device__ __forceinline__ unsigned short f2bf(float f) {
    union { float f; unsigned int i; } v; v.f = f;
    unsigned int r = v.i + 0x7FFF + ((v.i >> 16) & 1);
    return (unsigned short)(r >> 16);
}

// ---------------- K1: fp32 -> bf16 convert (x, Wq, Wk, Wv, Wo) ----------------
__global__ __launch_bounds__(256) void k_convert(
    const float* __restrict__ x, const float* __restrict__ wq,
    const float* __restrict__ wk, const float* __restrict__ wv,
    const float* __restrict__ wo, unsigned short* __restrict__ dst) {
    long t = (long)blockIdx.x * 256 + threadIdx.x;
    long base = t * 4;
    const long NX = 2097152, NW = 1048576;
    const float* src; long off;
    if (base < NX)            { src = x;  off = base; }
    else if (base < NX + NW)  { src = wq; off = base - NX; }
    else if (base < NX + 2*NW){ src = wk; off = base - NX - NW; }
    else if (base < NX + 3*NW){ src = wv; off = base - NX - 2*NW; }
    else                      { src = wo; off = base - NX - 3*NW; }
    float4 v = *(const float4*)(src + off);
    ushort4 o;
    o.x = f2bf(v.x); o.y = f2bf(v.y); o.z = f2bf(v.z); o.w = f2bf(v.w);
    *(ushort4*)(dst + base) = o;
}

// ---------------- K2: bias materialization (lower-triangle tiles) -------------
// bias[b][h][i][j] = (E_idx[clip(i-j)] + E_bar[bar+1]+E_pos[pos+1]+E_oct[oct+1]+E_semi[semi+1])[h] * 0.125
__global__ __launch_bounds__(256) void k_bias(
    const float* __restrict__ Eidx, const float* __restrict__ Ebar,
    const float* __restrict__ Epos, const float* __restrict__ Eoct,
    const float* __restrict__ Esemi,
    const int* __restrict__ barm, const int* __restrict__ posm,
    const int* __restrict__ octm, const int* __restrict__ semim,
    unsigned short* __restrict__ biasg) {
    int bid = blockIdx.x;
    int tj = bid & 15, ti = (bid >> 4) & 63, b = bid >> 10;
    int i0 = ti * 16, j0 = tj * 64;
    if (j0 > i0 + 15) return;   // strictly upper tile: never read by attention

    __shared__ float tbl[2416];          // Ebar(272) Epos(1536) Eoct(400) Esemi(208)
    __shared__ int   pk[16 * 65];        // packed indices, pad 65 (bank-safe)
    __shared__ float eidx_s[80 * 17];    // E_idx slice, pad 17 (bank-safe)

    int t = threadIdx.x;
    for (int i = t; i < 272;  i += 256) tbl[i]        = Ebar[i];
    for (int i = t; i < 1536; i += 256) tbl[272 + i]  = Epos[i];
    for (int i = t; i < 400;  i += 256) tbl[1808 + i] = Eoct[i];
    for (int i = t; i < 208;  i += 256) tbl[2208 + i] = Esemi[i];

    int rel_lo = i0 - j0 - 63; if (rel_lo < 0) rel_lo = 0;
    int rel_hi = i0 + 15 - j0;              // >= 0 for active tiles
    int nrel = rel_hi - rel_lo + 1;         // <= 79
    for (int idx = t; idx < nrel * 16; idx += 256) {
        int rr = idx >> 4, hh = idx & 15;
        eidx_s[rr * 17 + hh] = Eidx[(rel_lo + rr) * 16 + hh];
    }
    #pragma unroll
    for (int cc = 0; cc < 4; cc++) {
        int cell = t + cc * 256;
        int i = i0 + (cell >> 6), j = j0 + (cell & 63);
        long ij = ((long)b << 20) + ((long)i << 10) + j;
        int v = (barm[ij] + 1) | ((posm[ij] + 1) << 5) |
                ((octm[ij] + 1) << 12) | ((semim[ij] + 1) << 17);
        pk[(cell >> 6) * 65 + (cell & 63)] = v;
    }
    __syncthreads();

    int h = t >> 4, r = t & 15;
    int i = i0 + r;
    long orow = ((((long)(b * 16 + h)) << 10) + i) * 1024 + j0;
    #pragma unroll
    for (int q = 0; q < 8; q++) {
        short8 outv;
        #pragma unroll
        for (int e = 0; e < 8; e++) {
            int col = q * 8 + e;
            int p = pk[r * 65 + col];
            int j = j0 + col;
            int rel = i - j; if (rel < 0) rel = 0;
            float v = eidx_s[(rel - rel_lo) * 17 + h]
                    + tbl[(p & 31) * 16 + h]
                    + tbl[272  + ((p >> 5)  & 127) * 16 + h]
                    + tbl[1808 + ((p >> 12) & 31)  * 16 + h]
                    + tbl[2208 + ((p >> 17) & 15)  * 16 + h];
            outv[e] = (short)f2bf(v * 0.125f);
        }
        *(short8*)(biasg + orow + q * 8) = outv;
    }
}

// ---------------- K3/K5: bf16 GEMM  C[M][N] = A[M][1024] * B[N][1024]^T -------
// mode<0: mode=blockIdx.z in {0:Q(scale 1/8), 1:K, 2:V^T}; mode==3: fp32 out.
__global__ __launch_bounds__(256) void k_gemm(
    const unsigned short* __restrict__ A,
    const unsigned short* __restrict__ B0, const unsigned short* __restrict__ B1,
    const unsigned short* __restrict__ B2,
    unsigned short* __restrict__ qd, unsigned short* __restrict__ kd,
    unsigned short* __restrict__ vtd, float* __restrict__ outf, int mode) {
    __shared__ unsigned short As[64][72];
    __shared__ unsigned short Bs[64][72];
    int md = (mode < 0) ? (int)blockIdx.z : mode;
    const unsigned short* B = (md == 1) ? B1 : (md == 2) ? B2 : B0;
    int m0 = blockIdx.x * 64, n0 = blockIdx.y * 64;
    int t = threadIdx.x;
    int w = t >> 6, lane = t & 63, g = lane >> 4, c = lane & 15;
    int srow = t >> 2, scg = t & 3;
    const int K = 1024;
    f32x4 zero = {0.f, 0.f, 0.f, 0.f};
    f32x4 acc[4];
    acc[0] = zero; acc[1] = zero; acc[2] = zero; acc[3] = zero;

    for (int k0 = 0; k0 < K; k0 += 64) {
        __syncthreads();
        *(short8*)&As[srow][scg * 16]     = *(const short8*)(A + (long)(m0 + srow) * K + k0 + scg * 16);
        *(short8*)&As[srow][scg * 16 + 8] = *(const short8*)(A + (long)(m0 + srow) * K + k0 + scg * 16 + 8);
        *(short8*)&Bs[srow][scg * 16]     = *(const short8*)(B + (long)(n0 + srow) * K + k0 + scg * 16);
        *(short8*)&Bs[srow][scg * 16 + 8] = *(const short8*)(B + (long)(n0 + srow) * K + k0 + scg * 16 + 8);
        __syncthreads();
        #pragma unroll
        for (int kk = 0; kk < 2; kk++) {
            short8 a = *(const short8*)&As[w * 16 + c][kk * 32 + g * 8];
            #pragma unroll
            for (int jc = 0; jc < 4; jc++) {
                short8 bf = *(const short8*)&Bs[jc * 16 + c][kk * 32 + g * 8];
                acc[jc] = __builtin_amdgcn_mfma_f32_16x16x32_bf16(a, bf, acc[jc], 0, 0, 0);
            }
        }
    }

    if (md <= 1) {
        unsigned short* dst = (md == 0) ? qd : kd;
        float scale = (md == 0) ? 0.125f : 1.0f;
        #pragma unroll
        for (int r = 0; r < 4; r++) {
            int mm = m0 + w * 16 + g * 4 + r;
            int bb = mm >> 10, ii = mm & 1023;
            #pragma unroll
            for (int jc = 0; jc < 4; jc++) {
                int nn = n0 + jc * 16 + c;
                int hh = nn >> 6, dd = nn & 63;
                dst[(((long)(bb * 16 + hh) << 10) + ii) * 64 + dd] = f2bf(acc[jc][r] * scale);
            }
        }
    } else if (md == 2) {
        int mm0 = m0 + w * 16 + g * 4;
        int bb = mm0 >> 10, ii = mm0 & 1023;
        #pragma unroll
        for (int jc = 0; jc < 4; jc++) {
            int nn = n0 + jc * 16 + c;
            int hh = nn >> 6, dd = nn & 63;
            ushort4 pkv;
            pkv.x = f2bf(acc[jc][0]); pkv.y = f2bf(acc[jc][1]);
            pkv.z = f2bf(acc[jc][2]); pkv.w = f2bf(acc[jc][3]);
            *(ushort4*)&vtd[(((long)(bb * 16 + hh) << 6) + dd) * 1024 + ii] = pkv;
        }
    } else {
        #pragma unroll
        for (int r = 0; r < 4; r++) {
            long mm = m0 + w * 16 + g * 4 + r;
            #pragma unroll
            for (int jc = 0; jc < 4; jc++) {
                int nn = n0 + jc * 16 + c;
                outf[mm * 1024 + nn] = acc[jc][r];
            }
        }
    }
}

// ---------------- K4: fused causal flash attention with bias ------------------
// grid 512 = b(2) x h(16) x stripe(16 of 64 rows); 4 waves, wave = 16 rows.
__global__ __launch_bounds__(256) void k_attn(
    const unsigned short* __restrict__ Qs, const unsigned short* __restrict__ Ks,
    const unsigned short* __restrict__ VTs, const unsigned short* __restrict__ biasg,
    unsigned short* __restrict__ Os) {
    __shared__ unsigned short p_lds[4][16][32];
    int bid = blockIdx.x;
    int sid = bid & 15, h = (bid >> 4) & 15, b = bid >> 8;
    int stripe = (sid & 1) ? (15 - (sid >> 1)) : (sid >> 1);  // balance causal skew
    int w = threadIdx.x >> 6, lane = threadIdx.x & 63;
    int g = lane >> 4, c = lane & 15;
    int i0 = stripe * 64 + w * 16;

    long plane = ((long)(b * 16 + h)) << 16;               // 1024*64 per head
    const unsigned short* Qp = Qs + plane;
    const unsigned short* Kp = Ks + plane;
    const unsigned short* Vp = VTs + plane;                // [64][1024]
    const unsigned short* Bp = biasg + (((long)(b * 16 + h)) << 20);

    short8 q0 = *(const short8*)(Qp + (long)(i0 + c) * 64 + g * 8);
    short8 q1 = *(const short8*)(Qp + (long)(i0 + c) * 64 + 32 + g * 8);

    f32x4 zero = {0.f, 0.f, 0.f, 0.f};
    f32x4 o0 = zero, o1 = zero, o2 = zero, o3 = zero;
    float m[4], l[4];
    #pragma unroll
    for (int r = 0; r < 4; r++) { m[r] = -1e30f; l[r] = 0.f; }

    int nj = ((i0 + 15) >> 5) + 1;
    for (int jt = 0; jt < nj; jt++) {
        int j0 = jt * 32;
        short8 ka0 = *(const short8*)(Kp + (long)(j0 + c) * 64 + g * 8);
        short8 ka1 = *(const short8*)(Kp + (long)(j0 + c) * 64 + 32 + g * 8);
        short8 kb0 = *(const short8*)(Kp + (long)(j0 + 16 + c) * 64 + g * 8);
        short8 kb1 = *(const short8*)(Kp + (long)(j0 + 16 + c) * 64 + 32 + g * 8);
        f32x4 s0 = zero, s1 = zero;
        s0 = __builtin_amdgcn_mfma_f32_16x16x32_bf16(q0, ka0, s0, 0, 0, 0);
        s0 = __builtin_amdgcn_mfma_f32_16x16x32_bf16(q1, ka1, s0, 0, 0, 0);
        s1 = __builtin_amdgcn_mfma_f32_16x16x32_bf16(q0, kb0, s1, 0, 0, 0);
        s1 = __builtin_amdgcn_mfma_f32_16x16x32_bf16(q1, kb1, s1, 0, 0, 0);

        int j0c = j0 + c;
        #pragma unroll
        for (int r = 0; r < 4; r++) {
            int i = i0 + g * 4 + r;
            const unsigned short* bp = Bp + (long)i * 1024;
            s0[r] += bf2f(bp[j0c]);
            s1[r] += bf2f(bp[j0c + 16]);
            if (j0c > i)      s0[r] = -1e30f;
            if (j0c + 16 > i) s1[r] = -1e30f;
        }
        float pj0[4], pj1[4];
        #pragma unroll
        for (int r = 0; r < 4; r++) {
            float mx = fmaxf(s0[r], s1[r]);
            mx = fmaxf(mx, __shfl_xor(mx, 1));
            mx = fmaxf(mx, __shfl_xor(mx, 2));
            mx = fmaxf(mx, __shfl_xor(mx, 4));
            mx = fmaxf(mx, __shfl_xor(mx, 8));
            float mn = fmaxf(m[r], mx);
            float alpha = exp2f((m[r] - mn) * LOG2E);
            float p0 = exp2f((s0[r] - mn) * LOG2E);
            float p1 = exp2f((s1[r] - mn) * LOG2E);
            float rs = p0 + p1;
            rs += __shfl_xor(rs, 1); rs += __shfl_xor(rs, 2);
            rs += __shfl_xor(rs, 4); rs += __shfl_xor(rs, 8);
            l[r] = l[r] * alpha + rs;
            m[r] = mn;
            o0[r] *= alpha; o1[r] *= alpha; o2[r] *= alpha; o3[r] *= alpha;
            pj0[r] = p0; pj1[r] = p1;
        }
        #pragma unroll
        for (int r = 0; r < 4; r++) {
            p_lds[w][g * 4 + r][c]      = f2bf(pj0[r]);
            p_lds[w][g * 4 + r][16 + c] = f2bf(pj1[r]);
        }
        short8 pf = *(const short8*)&p_lds[w][c][g * 8];
        const unsigned short* vb = Vp + (long)c * 1024 + j0 + g * 8;
        short8 v0 = *(const short8*)(vb);
        short8 v1 = *(const short8*)(vb + 16 * 1024);
        short8 v2 = *(const short8*)(vb + 32 * 1024);
        short8 v3 = *(const short8*)(vb + 48 * 1024);
        o0 = __builtin_amdgcn_mfma_f32_16x16x32_bf16(pf, v0, o0, 0, 0, 0);
        o1 = __builtin_amdgcn_mfma_f32_16x16x32_bf16(pf, v1, o1, 0, 0, 0);
        o2 = __builtin_amdgcn_mfma_f32_16x16x32_bf16(pf, v2, o2, 0, 0, 0);
        o3 = __builtin_amdgcn_mfma_f32_16x16x32_bf16(pf, v3, o3, 0, 0, 0);
    }
    #pragma unroll
    for (int r = 0; r < 4; r++) {
        float inv = 1.0f / l[r];
        int i = i0 + g * 4 + r;
        unsigned short* op = Os + ((long)(b * 1024 + i)) * 1024 + h * 64;
        op[c]      = f2bf(o0[r] * inv);
        op[16 + c] = f2bf(o1[r] * inv);
        op[32 + c] = f2bf(o2[r] * inv);
        op[48 + c] = f2bf(o3[r] * inv);
    }
}

// ------------------------------- launch ---------------------------------------
extern "C" void kernel_launch(void* const* d_in, const int* in_sizes, int n_in,
                              void* d_out, int out_size, void* d_ws, size_t ws_size,
                              hipStream_t stream) {
    const float* x     = (const float*)d_in[0];
    const float* Wq    = (const float*)d_in[1];
    const float* Wk    = (const float*)d_in[2];
    const float* Wv    = (const float*)d_in[3];
    const float* Wo    = (const float*)d_in[4];
    const float* Eidx  = (const float*)d_in[5];
    const float* Ebar  = (const float*)d_in[6];
    const float* Epos  = (const float*)d_in[7];
    const float* Eoct  = (const float*)d_in[8];
    const float* Esemi = (const float*)d_in[9];
    const int* barm    = (const int*)d_in[10];
    const int* posm    = (const int*)d_in[11];
    const int* octm    = (const int*)d_in[12];
    const int* semim   = (const int*)d_in[13];
    float* outf = (float*)d_out;

    unsigned short* w = (unsigned short*)d_ws;
    unsigned short* XB   = w;                   // 2M
    unsigned short* WQB  = w + 2097152;         // 1M
    unsigned short* WKB  = w + 3145728;
    unsigned short* WVB  = w + 4194304;
    unsigned short* WOB  = w + 5242880;
    unsigned short* QS   = w + 6291456;         // 2M (b,h,n,d)
    unsigned short* KS   = w + 8388608;
    unsigned short* VTS  = w + 10485760;        // (b,h,d,n)
    unsigned short* OS   = w + 12582912;        // (b,n,h*d)
    unsigned short* BIAS = w + 14680064;        // 32M (b,h,n,n)

    k_convert<<<6144, 256, 0, stream>>>(x, Wq, Wk, Wv, Wo, w);
    k_bias<<<2048, 256, 0, stream>>>(Eidx, Ebar, Epos, Eoct, Esemi,
                                     barm, posm, octm, semim, BIAS);
    k_gemm<<<dim3(32, 16, 3), 256, 0, stream>>>(XB, WQB, WKB, WVB,
                                                QS, KS, VTS, nullptr, -1);
    k_attn<<<512, 256, 0, stream>>>(QS, KS, VTS, BIAS, OS);
    k_gemm<<<dim3(32, 16, 1), 256, 0, stream>>>(OS, WOB, WOB, WOB,
                                                QS, KS, VTS, outf, 3);
}